// Round 2
// baseline (885.044 us; speedup 1.0000x reference)
//
#include <hip/hip_runtime.h>
#include <hip/hip_bf16.h>

#define E_ 8
#define D_ 1024
#define F_ 4096
#define G_ 2048

typedef __attribute__((ext_vector_type(8))) short bf16x8;
typedef __attribute__((ext_vector_type(4))) float f32x4;
typedef __attribute__((ext_vector_type(16))) float f32x16;
typedef __attribute__((ext_vector_type(8))) unsigned short u16x8;
typedef unsigned short u16;
typedef unsigned int u32;

#define MFMA32 __builtin_amdgcn_mfma_f32_32x32x16_bf16
#define FENCE() asm volatile("" ::: "memory")
#define BAR()                          \
  do {                                 \
    FENCE();                           \
    __builtin_amdgcn_s_barrier();      \
    FENCE();                           \
  } while (0)

// round-to-nearest-even fp32 -> bf16 (branchless)
__device__ __forceinline__ u16 f2bf(float f) {
  u32 u = __float_as_uint(f);
  u = (u + 0x7fffu + ((u >> 16) & 1u)) >> 16;
  return (u16)u;
}

// async global->LDS, 16B per lane; LDS dest = base + lane*16 (wave-uniform base)
__device__ __forceinline__ void gld_lds16(const void* g, void* l) {
  __builtin_amdgcn_global_load_lds(
      (const __attribute__((address_space(1))) u32*)g,
      (__attribute__((address_space(3))) u32*)l, 16, 0, 0);
}

// ---- stage one 128x64 bf16 half-tile (16KB) from global row-major (stride ld)
// into LDS with XOR-8 group swizzle: LDS slot (row, s) holds global 16B-group
// g = s ^ (row&7). LDS dest LINEAR (gld_lds requirement); swizzle applied on
// the per-lane GLOBAL source address (rule #21). 512 thr x 2 x 16B.
__device__ __forceinline__ void stage_half(const u16* __restrict__ g, int ld,
                                           char* l, int tid) {
  const int wb = (tid & ~63) * 16;  // wave-uniform LDS byte base (lane*16 added by HW)
#pragma unroll
  for (int j = 0; j < 2; j++) {
    const int idx = j * 512 + tid;           // 16B slot index 0..1023
    const int row = idx >> 3;                // 0..127
    const int grp = (idx & 7) ^ (row & 7);   // swizzled global group
    gld_lds16(g + (size_t)row * ld + grp * 8, l + j * 8192 + wb);
  }
}

// fragment read: row r (bf16, 64-elem rows), 16B group gw (0..7 = k-group).
// inverse of the stage swizzle; conflict-free (consecutive lanes -> distinct groups).
__device__ __forceinline__ bf16x8 ld_frag(const u16* base, int r, int gw) {
  return *(const bf16x8*)(base + r * 64 + ((gw ^ (r & 7)) << 3));
}

// ---------------- elementwise fp32 -> bf16 ----------------
__global__ __launch_bounds__(256) void k_cvt(const float* __restrict__ in,
                                             u16* __restrict__ out, int n8) {
  int i = blockIdx.x * 256 + threadIdx.x;
  if (i >= n8) return;
  const float4* p = (const float4*)in + (size_t)i * 2;
  float4 a = p[0], b = p[1];
  u16x8 o;
  o[0] = f2bf(a.x); o[1] = f2bf(a.y); o[2] = f2bf(a.z); o[3] = f2bf(a.w);
  o[4] = f2bf(b.x); o[5] = f2bf(b.y); o[6] = f2bf(b.z); o[7] = f2bf(b.w);
  *(u16x8*)(out + (size_t)i * 8) = o;
}

// ---- transpose+convert: in [B][R][C] fp32 -> out [B][C][R] bf16, 64x64 tiles ----
__global__ __launch_bounds__(256) void k_tcvt(const float* __restrict__ in,
                                              u16* __restrict__ out, int R, int C) {
  __shared__ __align__(16) u16 Tt[64 * 72];
  size_t base = (size_t)blockIdx.z * (size_t)R * (size_t)C;
  in += base; out += base;
  const int c0 = blockIdx.x * 64, r0 = blockIdx.y * 64;
  const int tid = threadIdx.x;
  {
    const int cq = tid & 15, rr = tid >> 4;
    const float* ip = in + (size_t)(r0 + rr) * C + c0 + cq * 4;
#pragma unroll
    for (int i = 0; i < 4; i++) {
      float4 v = *(const float4*)(ip + (size_t)(16 * i) * C);
      const int r = rr + 16 * i, c = cq * 4;
      Tt[(c + 0) * 72 + r] = f2bf(v.x);
      Tt[(c + 1) * 72 + r] = f2bf(v.y);
      Tt[(c + 2) * 72 + r] = f2bf(v.z);
      Tt[(c + 3) * 72 + r] = f2bf(v.w);
    }
  }
  __syncthreads();
  {
    const int rq = tid & 7, cc0 = tid >> 3;
#pragma unroll
    for (int i = 0; i < 2; i++) {
      const int cc = cc0 + 32 * i;
      u16x8 v = *(const u16x8*)(Tt + cc * 72 + rq * 8);
      *(u16x8*)(out + (size_t)(c0 + cc) * R + r0 + rq * 8) = v;
    }
  }
}

// ---------------- fused GEMM1+GEMM2 + SwiGLU, persistent bn-loop ----------------
// H = silu(X@W1) * (X@W2) per expert. 32x32x16 MFMA.
// Per block: A panel rows [bm,bm+256), bn-loop over 8 n-tiles of 128 => one
// seamless 128-tile pipelined K-loop (single prologue per block; 256 blocks = 1/CU).
// 8 waves 4m x 2n; per wave 64x64 per gemm: mb=2, nb=2, ks=4 -> 32 MFMA/tile.
// LDS 128KB = 2 bufs x {A0,A1,B1,B2} x 16KB. 4 phases/tile, 8 MFMA each.
// Stage: ph1 A0(u+1), ph2 A1(u+1), ph3 B1(u+2), ph4 B2(u+2)+vmcnt(4).
__global__ __launch_bounds__(512, 2) void k_mlp1(const u16* __restrict__ X,
                                                 const u16* __restrict__ W1t,
                                                 const u16* __restrict__ W2t,
                                                 u16* __restrict__ H) {
  __shared__ __align__(128) char smem[131072];
  u16* lp = (u16*)smem;
  const int e = blockIdx.z;
  const u16* Ag  = X   + (size_t)e * G_ * D_;
  const u16* B1g = W1t + (size_t)e * F_ * D_;
  const u16* B2g = W2t + (size_t)e * F_ * D_;
  u16* Hp = H + (size_t)e * G_ * F_;
  const int bm = blockIdx.y * 256;
  const int bn0 = blockIdx.x * 1024;               // 8 n-tiles of 128
  const int tid = threadIdx.x, wave = tid >> 6, lane = tid & 63;
  const int wm = wave >> 1, wn = wave & 1;         // 4m x 2n
  const int l32 = lane & 31, lhi = lane >> 5;
  const int NU = 8 * (D_ / 64);                    // 128 tiles

  f32x16 z;
#pragma unroll
  for (int i = 0; i < 16; i++) z[i] = 0.f;
  f32x16 acc1[2][2], acc2[2][2];
#pragma unroll
  for (int i = 0; i < 2; i++)
#pragma unroll
    for (int j = 0; j < 2; j++) { acc1[i][j] = z; acc2[i][j] = z; }

  const int arb = (wm & 1) * 64;   // A row base within 128-row half
  const int brb = wn * 64;         // B row base within 128-row panel

#define KOF(u) (((u) & 15) * 64)
#define BNF(u) (bn0 + ((u) >> 4) * 128)

  // prologue: A(0) halves -> buf0; B(0) -> buf0; B(1) -> buf1
  stage_half(Ag  + (size_t)bm * D_,                        D_, smem,                 tid);
  stage_half(Ag  + (size_t)(bm + 128) * D_,                D_, smem + 16384,         tid);
  stage_half(B1g + (size_t)BNF(0) * D_,                    D_, smem + 32768,         tid);
  stage_half(B2g + (size_t)BNF(0) * D_,                    D_, smem + 49152,         tid);
  stage_half(B1g + (size_t)BNF(1) * D_ + KOF(1),           D_, smem + 65536 + 32768, tid);
  stage_half(B2g + (size_t)BNF(1) * D_ + KOF(1),           D_, smem + 65536 + 49152, tid);
  asm volatile("s_waitcnt vmcnt(0)" ::: "memory");
  BAR();

  for (int u = 0; u < NU; ++u) {
    const int q = u & 1, qn = q ^ 1;
    const u16* Aw  = lp + q * 32768 + (wm >> 1) * 8192;
    const u16* B1w = lp + q * 32768 + 16384;
    const u16* B2w = lp + q * 32768 + 24576;
    bf16x8 af[2][4], b1f[2][4], b2f[2][4];

    // ---- phase 1: read B1 all + A mb0; stage A0(u+1); MFMA gemm1 mb0 ----
#pragma unroll
    for (int nb = 0; nb < 2; nb++)
#pragma unroll
      for (int ks = 0; ks < 4; ks++)
        b1f[nb][ks] = ld_frag(B1w, brb + nb * 32 + l32, 2 * ks + lhi);
#pragma unroll
    for (int ks = 0; ks < 4; ks++)
      af[0][ks] = ld_frag(Aw, arb + l32, 2 * ks + lhi);
    if (u + 1 < NU)
      stage_half(Ag + (size_t)bm * D_ + KOF(u + 1), D_, smem + qn * 65536, tid);
    BAR();
    __builtin_amdgcn_s_setprio(1);
#pragma unroll
    for (int ks = 0; ks < 4; ks++)
#pragma unroll
      for (int nb = 0; nb < 2; nb++)
        acc1[0][nb] = MFMA32(af[0][ks], b1f[nb][ks], acc1[0][nb], 0, 0, 0);
    __builtin_amdgcn_s_setprio(0);
    BAR();

    // ---- phase 2: read A mb1; stage A1(u+1); MFMA gemm1 mb1 ----
#pragma unroll
    for (int ks = 0; ks < 4; ks++)
      af[1][ks] = ld_frag(Aw, arb + 32 + l32, 2 * ks + lhi);
    if (u + 1 < NU)
      stage_half(Ag + (size_t)(bm + 128) * D_ + KOF(u + 1), D_,
                 smem + qn * 65536 + 16384, tid);
    BAR();
    __builtin_amdgcn_s_setprio(1);
#pragma unroll
    for (int ks = 0; ks < 4; ks++)
#pragma unroll
      for (int nb = 0; nb < 2; nb++)
        acc1[1][nb] = MFMA32(af[1][ks], b1f[nb][ks], acc1[1][nb], 0, 0, 0);
    __builtin_amdgcn_s_setprio(0);
    BAR();

    // ---- phase 3: read B2 all; stage B1(u+2); MFMA gemm2 mb0 ----
#pragma unroll
    for (int nb = 0; nb < 2; nb++)
#pragma unroll
      for (int ks = 0; ks < 4; ks++)
        b2f[nb][ks] = ld_frag(B2w, brb + nb * 32 + l32, 2 * ks + lhi);
    if (u + 2 < NU)
      stage_half(B1g + (size_t)BNF(u + 2) * D_ + KOF(u + 2), D_,
                 smem + q * 65536 + 32768, tid);
    BAR();
    __builtin_amdgcn_s_setprio(1);
#pragma unroll
    for (int ks = 0; ks < 4; ks++)
#pragma unroll
      for (int nb = 0; nb < 2; nb++)
        acc2[0][nb] = MFMA32(af[0][ks], b2f[nb][ks], acc2[0][nb], 0, 0, 0);
    __builtin_amdgcn_s_setprio(0);
    BAR();

    // ---- phase 4: stage B2(u+2); counted vmcnt; MFMA gemm2 mb1 ----
    if (u + 2 < NU) {
      stage_half(B2g + (size_t)BNF(u + 2) * D_ + KOF(u + 2), D_,
                 smem + q * 65536 + 49152, tid);
      asm volatile("s_waitcnt vmcnt(4)" ::: "memory");
    } else {
      asm volatile("s_waitcnt vmcnt(0)" ::: "memory");
    }
    BAR();
    __builtin_amdgcn_s_setprio(1);
#pragma unroll
    for (int ks = 0; ks < 4; ks++)
#pragma unroll
      for (int nb = 0; nb < 2; nb++)
        acc2[1][nb] = MFMA32(af[1][ks], b2f[nb][ks], acc2[1][nb], 0, 0, 0);
    __builtin_amdgcn_s_setprio(0);
    BAR();

    // ---- per-bn epilogue: SwiGLU + store, reset acc ----
    if ((u & 15) == 15) {
      const int bn = BNF(u);
#pragma unroll
      for (int mb = 0; mb < 2; mb++)
#pragma unroll
        for (int nb = 0; nb < 2; nb++) {
#pragma unroll
          for (int r = 0; r < 16; r++) {
            float mm = acc1[mb][nb][r], g = acc2[mb][nb][r];
            float h = (mm / (1.f + __expf(-mm))) * g;
            int row = bm + wm * 64 + mb * 32 + (r & 3) + 8 * (r >> 2) + 4 * lhi;
            int col = bn + wn * 64 + nb * 32 + l32;
            Hp[(size_t)row * F_ + col] = f2bf(h);
          }
          acc1[mb][nb] = z;
          acc2[mb][nb] = z;
        }
    }
  }
#undef KOF
#undef BNF
}

// ---------------- GEMM3: out = H @ W3 (256x256 tile, 32x32 MFMA) ----------------
// 8 waves 2m x 4n; per wave 128x64: mb=4, nb=2, ks=4 -> 32 MFMA/tile.
// LDS 128KB = 2 bufs x {A0,A1,B0,B1} x 16KB. 4 phases/tile, 8 MFMA each.
// Stage: ph1 A0(t+1), ph2 A1(t+1), ph3 B0(t+2), ph4 B1(t+2)+vmcnt(4).
__global__ __launch_bounds__(512, 2) void k_mlp2(const u16* __restrict__ H,
                                                 const u16* __restrict__ W3t,
                                                 float* __restrict__ O) {
  __shared__ __align__(128) char smem[131072];
  u16* lp = (u16*)smem;
  const int e = blockIdx.z;
  const u16* Ag = H   + (size_t)e * G_ * F_;
  const u16* Bg = W3t + (size_t)e * D_ * F_;
  float* C = O + (size_t)e * G_ * D_;
  const int bm = blockIdx.y * 256, bn = blockIdx.x * 256;
  const int tid = threadIdx.x, wave = tid >> 6, lane = tid & 63;
  const int wm = wave >> 2, wn = wave & 3;         // 2m x 4n
  const int l32 = lane & 31, lhi = lane >> 5;
  const int NT = F_ / 64;                          // 64 tiles

  f32x16 z;
#pragma unroll
  for (int i = 0; i < 16; i++) z[i] = 0.f;
  f32x16 acc[4][2];
#pragma unroll
  for (int i = 0; i < 4; i++)
#pragma unroll
    for (int j = 0; j < 2; j++) acc[i][j] = z;

  const int brb = (wn & 1) * 64;   // B row base within 128-row half

  // prologue: A(0) halves, B(0) halves, B(1) halves
  stage_half(Ag + (size_t)bm * F_,               F_, smem,                 tid);
  stage_half(Ag + (size_t)(bm + 128) * F_,       F_, smem + 16384,         tid);
  stage_half(Bg + (size_t)bn * F_,               F_, smem + 32768,         tid);
  stage_half(Bg + (size_t)(bn + 128) * F_,       F_, smem + 49152,         tid);
  stage_half(Bg + (size_t)bn * F_ + 64,          F_, smem + 65536 + 32768, tid);
  stage_half(Bg + (size_t)(bn + 128) * F_ + 64,  F_, smem + 65536 + 49152, tid);
  asm volatile("s_waitcnt vmcnt(0)" ::: "memory");
  BAR();

  for (int t = 0; t < NT; ++t) {
    const int q = t & 1, qn = q ^ 1;
    const u16* Aw = lp + q * 32768 + wm * 8192;
    const u16* Bw = lp + q * 32768 + 16384 + (wn >> 1) * 8192;
    bf16x8 bf[2][4], af[4];

    // ---- phase 1: read B all + A mb0; stage A0(t+1) ----
#pragma unroll
    for (int nb = 0; nb < 2; nb++)
#pragma unroll
      for (int ks = 0; ks < 4; ks++)
        bf[nb][ks] = ld_frag(Bw, brb + nb * 32 + l32, 2 * ks + lhi);
#pragma unroll
    for (int ks = 0; ks < 4; ks++)
      af[ks] = ld_frag(Aw, l32, 2 * ks + lhi);
    if (t + 1 < NT)
      stage_half(Ag + (size_t)bm * F_ + (t + 1) * 64, F_, smem + qn * 65536, tid);
    BAR();
    __builtin_amdgcn_s_setprio(1);
#pragma unroll
    for (int ks = 0; ks < 4; ks++)
#pragma unroll
      for (int nb = 0; nb < 2; nb++)
        acc[0][nb] = MFMA32(af[ks], bf[nb][ks], acc[0][nb], 0, 0, 0);
    __builtin_amdgcn_s_setprio(0);
    BAR();

    // ---- phase 2: read A mb1; stage A1(t+1) ----
#pragma unroll
    for (int ks = 0; ks < 4; ks++)
      af[ks] = ld_frag(Aw, 32 + l32, 2 * ks + lhi);
    if (t + 1 < NT)
      stage_half(Ag + (size_t)(bm + 128) * F_ + (t + 1) * 64, F_,
                 smem + qn * 65536 + 16384, tid);
    BAR();
    __builtin_amdgcn_s_setprio(1);
#pragma unroll
    for (int ks = 0; ks < 4; ks++)
#pragma unroll
      for (int nb = 0; nb < 2; nb++)
        acc[1][nb] = MFMA32(af[ks], bf[nb][ks], acc[1][nb], 0, 0, 0);
    __builtin_amdgcn_s_setprio(0);
    BAR();

    // ---- phase 3: read A mb2; stage B0(t+2) ----
#pragma unroll
    for (int ks = 0; ks < 4; ks++)
      af[ks] = ld_frag(Aw, 64 + l32, 2 * ks + lhi);
    if (t + 2 < NT)
      stage_half(Bg + (size_t)bn * F_ + (t + 2) * 64, F_,
                 smem + q * 65536 + 32768, tid);
    BAR();
    __builtin_amdgcn_s_setprio(1);
#pragma unroll
    for (int ks = 0; ks < 4; ks++)
#pragma unroll
      for (int nb = 0; nb < 2; nb++)
        acc[2][nb] = MFMA32(af[ks], bf[nb][ks], acc[2][nb], 0, 0, 0);
    __builtin_amdgcn_s_setprio(0);
    BAR();

    // ---- phase 4: read A mb3; stage B1(t+2); counted vmcnt ----
#pragma unroll
    for (int ks = 0; ks < 4; ks++)
      af[ks] = ld_frag(Aw, 96 + l32, 2 * ks + lhi);
    if (t + 2 < NT) {
      stage_half(Bg + (size_t)(bn + 128) * F_ + (t + 2) * 64, F_,
                 smem + q * 65536 + 49152, tid);
      asm volatile("s_waitcnt vmcnt(4)" ::: "memory");
    } else {
      asm volatile("s_waitcnt vmcnt(0)" ::: "memory");
    }
    BAR();
    __builtin_amdgcn_s_setprio(1);
#pragma unroll
    for (int ks = 0; ks < 4; ks++)
#pragma unroll
      for (int nb = 0; nb < 2; nb++)
        acc[3][nb] = MFMA32(af[ks], bf[nb][ks], acc[3][nb], 0, 0, 0);
    __builtin_amdgcn_s_setprio(0);
    BAR();
  }

#pragma unroll
  for (int mb = 0; mb < 4; mb++)
#pragma unroll
    for (int nb = 0; nb < 2; nb++)
#pragma unroll
      for (int r = 0; r < 16; r++) {
        int row = bm + wm * 128 + mb * 32 + (r & 3) + 8 * (r >> 2) + 4 * lhi;
        int col = bn + wn * 64 + nb * 32 + l32;
        C[(size_t)row * D_ + col] = acc[mb][nb][r];
      }
}

extern "C" void kernel_launch(void* const* d_in, const int* in_sizes, int n_in,
                              void* d_out, int out_size, void* d_ws, size_t ws_size,
                              hipStream_t stream) {
  const float* x  = (const float*)d_in[0];  // [E*G, D]
  const float* w1 = (const float*)d_in[1];  // [E*D, F]
  const float* w2 = (const float*)d_in[2];  // [E*D, F]
  const float* w3 = (const float*)d_in[3];  // [E*F, D]
  float* out = (float*)d_out;               // [E*G, D] fp32
  char* ws = (char*)d_ws;

  // workspace layout (288MB total):
  //   Xb  [0,   32MB)  bf16 [E][G][D]     (dead after k_mlp1)
  //   W1t [32,  96MB)  bf16 [E][F][D]     (dead after k_mlp1)
  //   W2t [96, 160MB)  bf16 [E][F][D]     (dead after k_mlp1)
  //   Hb  [160,288MB)  bf16 [E][G][F]
  //   W3t [0,   64MB)  bf16 [E][D][F]     (written AFTER k_mlp1; aliases Xb/W1t-head)
  u16* Xb  = (u16*)(ws);
  u16* W1t = (u16*)(ws + (size_t)32 * 1024 * 1024);
  u16* W2t = (u16*)(ws + (size_t)96 * 1024 * 1024);
  u16* Hb  = (u16*)(ws + (size_t)160 * 1024 * 1024);
  u16* W3t = (u16*)(ws);

  // 1) X fp32->bf16
  k_cvt<<<dim3((E_ * G_ * D_ / 8 + 255) / 256), dim3(256), 0, stream>>>(
      x, Xb, E_ * G_ * D_ / 8);
  // 2) W1,W2: [D,F] -> [F,D] bf16
  k_tcvt<<<dim3(F_ / 64, D_ / 64, E_), dim3(256), 0, stream>>>(w1, W1t, D_, F_);
  k_tcvt<<<dim3(F_ / 64, D_ / 64, E_), dim3(256), 0, stream>>>(w2, W2t, D_, F_);
  // 3) hidden = silu(X@W1) * (X@W2)  [persistent bn-loop, 256 blocks = 1/CU]
  k_mlp1<<<dim3(F_ / 128 / 8, G_ / 256, E_), dim3(512), 0, stream>>>(Xb, W1t, W2t, Hb);
  // 4) W3: [F,D] -> [D,F] bf16 (into region freed by Xb/W1t)
  k_tcvt<<<dim3(D_ / 64, F_ / 64, E_), dim3(256), 0, stream>>>(w3, W3t, F_, D_);
  // 5) out = hidden @ W3   [256x256 tile]
  k_mlp2<<<dim3(D_ / 256, G_ / 256, E_), dim3(512), 0, stream>>>(Hb, W3t, out);
}